// Round 7
// baseline (805.635 us; speedup 1.0000x reference)
//
#include <hip/hip_runtime.h>
#include <cstdint>
#include <cstddef>

// ---------------------------------------------------------------------------
// WaveInterference: x -> Q,K,V (Linear) -> softmax(QK^T/sqrt(512)) V -> Wo
// B=4, S=4096, H=1024.  Heavy GEMMs in bf16 MFMA (fp32 accumulate).
//
// R6 -> R7: PV was 530 TF at 2 blocks/CU (512 tiles/pair is structural).
// If ws_size >= 210 MB, take a 6th slab so ALL FOUR P matrices stay live
// (P0->Vb, P1->xb, P2->slab5, P3->Kb after the last scores gemm) and run ONE
// PV dispatch: z=4 batches, 1024 blocks, Klen=4096, A written into dead Q
// slots.  Fallback: R6 pair path.  V-transpose rewritten on ushort2 (4B)
// accesses, 64x64 tiles, pad-65 LDS (2-way conflicts only = free).
// ---------------------------------------------------------------------------

typedef unsigned short ushort_t;
typedef __bf16 bf16x8 __attribute__((ext_vector_type(8)));
typedef float f32x4 __attribute__((ext_vector_type(4)));
typedef unsigned short ushort4v __attribute__((ext_vector_type(4)));

struct Ptr4 { const float* p[4]; };      // cvt sources
struct BPtr4 { const ushort_t* p[4]; };  // per-z A/B operand tables
struct Bias4 { const float* p[4]; };
struct Alpha4 { float a[4]; };

__device__ __forceinline__ ushort_t f32_to_bf16(float f) {
  union { float f; unsigned int u; } x;
  x.f = f;
  unsigned int r = x.u + 0x7FFFu + ((x.u >> 16) & 1u);  // round-to-nearest-even
  return (ushort_t)(r >> 16);
}

// async 16B global -> LDS (LDS dst must be wave-uniform base + lane*16)
__device__ __forceinline__ void gl2lds16(const ushort_t* g, ushort_t* l) {
  __builtin_amdgcn_global_load_lds(
      (__attribute__((address_space(1))) void*)(g),
      (__attribute__((address_space(3))) void*)(l),
      16, 0, 0);
}

// ---------------------------------------------------------------------------
// fp32 -> bf16, 4 elems/thread; grid.z selects among 4 (src, dst-slab) pairs
// ---------------------------------------------------------------------------
__global__ __launch_bounds__(256) void cvt_f32_bf16(
    Ptr4 srcs, ushort_t* __restrict__ out0, size_t zstride, int n4) {
  int i = blockIdx.x * 256 + threadIdx.x;
  if (i >= n4) return;
  const float* in = srcs.p[blockIdx.z & 3];
  ushort_t* out = out0 + zstride * blockIdx.z;
  float4 f = reinterpret_cast<const float4*>(in)[i];
  ushort4v o;
  o.x = f32_to_bf16(f.x);
  o.y = f32_to_bf16(f.y);
  o.z = f32_to_bf16(f.z);
  o.w = f32_to_bf16(f.w);
  reinterpret_cast<ushort4v*>(out)[i] = o;
}

// ---------------------------------------------------------------------------
// C[m,n] = alpha_z * sum_{k<Klen} A_z[m,k]*B_z[n,k] (+ bias_z[n]).  A,B bf16
// row-major with leading dims lda/ldb; C leading dim ldc, advanced z*zC.
// Per-z operand tables enable fused QKV (z=proj) and batched PV (z=batch).
// 128x128 tile, BK=64, 4 waves (2x2), 16x16x32 bf16 MFMA, global_load_lds
// width-16 staging, XCD band swizzle.  Requires gridDim.y % 8 == 0.
// ---------------------------------------------------------------------------
template <typename OutT>
__global__ __launch_bounds__(256, 3) void gemm_bt(
    BPtr4 a4, BPtr4 b4, Bias4 bz, Alpha4 al, OutT* __restrict__ C,
    int Klen, int lda, int ldb, int ldc, size_t zC) {
  __shared__ __align__(16) ushort_t As[128 * 64];
  __shared__ __align__(16) ushort_t Bs[128 * 64];

  const int z = blockIdx.z & 3;
  const ushort_t* __restrict__ A = a4.p[z];
  const ushort_t* __restrict__ B = b4.p[z];
  const float* bias = bz.p[z];
  const float alpha = al.a[z];
  C += (size_t)blockIdx.z * zC;

  // --- XCD band swizzle.  HW: xcd = linear_block_id % 8.  Each XCD owns a
  // horizontal band of gridDim.y/8 block-rows, walked column-major so the A
  // band stays L2-resident while B streams once per XCD. ---
  const int flat = blockIdx.x + gridDim.x * blockIdx.y;
  const int bandH = gridDim.y >> 3;
  const int xcd = flat & 7;
  const int slot = flat >> 3;
  const int bxs = slot / bandH;
  const int bys = xcd * bandH + (slot - bxs * bandH);
  const int blockRow = bys * 128;
  const int blockCol = bxs * 128;

  const int tid = threadIdx.x;
  const int lane = tid & 63;
  const int wave = tid >> 6;
  const int wm = wave >> 1;  // wave row (0..1), 64 rows each
  const int wn = wave & 1;   // wave col (0..1), 64 cols each

  // staging: each wave covers 32 rows of the 128x64 tile in 4 issues of 8 rows
  const int srow = wave * 32 + (lane >> 3);
  const int scol = (lane & 7) * 8;  // bf16 elems in the 64-wide K slab
  const ushort_t* Ag = A + (size_t)(blockRow + srow) * lda + scol;
  const ushort_t* Bg = B + (size_t)(blockCol + srow) * ldb + scol;
  ushort_t* Al = &As[srow * 64 + scol];  // = As + (wavebase + lane*16B)
  ushort_t* Bl = &Bs[srow * 64 + scol];

  const int lm = lane & 15;    // m (A frag) / n (B frag)
  const int quad = lane >> 4;  // 0..3 -> k offset quad*8

  f32x4 acc[4][4] = {};

  for (int k0 = 0; k0 < Klen; k0 += 64) {
#pragma unroll
    for (int j = 0; j < 4; ++j) {
      gl2lds16(Ag + (size_t)j * 8 * lda + k0, Al + j * 8 * 64);
      gl2lds16(Bg + (size_t)j * 8 * ldb + k0, Bl + j * 8 * 64);
    }
    __syncthreads();  // compiler emits vmcnt(0) drain before barrier
#pragma unroll
    for (int kk = 0; kk < 64; kk += 32) {
      bf16x8 af[4], bfr[4];
#pragma unroll
      for (int i = 0; i < 4; ++i) {
        af[i] = *reinterpret_cast<const bf16x8*>(
            &As[(wm * 64 + i * 16 + lm) * 64 + kk + quad * 8]);
        bfr[i] = *reinterpret_cast<const bf16x8*>(
            &Bs[(wn * 64 + i * 16 + lm) * 64 + kk + quad * 8]);
      }
#pragma unroll
      for (int i = 0; i < 4; ++i)
#pragma unroll
        for (int j = 0; j < 4; ++j)
          acc[i][j] = __builtin_amdgcn_mfma_f32_16x16x32_bf16(
              af[i], bfr[j], acc[i][j], 0, 0, 0);
    }
    __syncthreads();
  }

  // epilogue: C/D layout col = lane&15 (n), row = quad*4 + reg (m)
  const int mBase = blockRow + wm * 64 + quad * 4;
  const int nBase = blockCol + wn * 64 + lm;
#pragma unroll
  for (int j = 0; j < 4; ++j) {
    const int n = nBase + j * 16;
    const float bv = bias ? bias[n] : 0.0f;
#pragma unroll
    for (int i = 0; i < 4; ++i) {
#pragma unroll
      for (int r = 0; r < 4; ++r) {
        const int m = mBase + i * 16 + r;
        float v = acc[i][j][r] * alpha + bv;
        if constexpr (sizeof(OutT) == 2)
          C[(size_t)m * ldc + n] = f32_to_bf16(v);
        else
          C[(size_t)m * ldc + n] = v;
      }
    }
  }
}

// ---------------------------------------------------------------------------
// bf16 transpose via ushort2 (4B) accesses: out[c][r] = in[r][c] per batch.
// 64x64 elem tiles; LDS row pitch 65 u2 -> only 2-way bank conflicts (free).
// grid (cols/64, rows/64, batches), block 256.  rows, cols even.
// ---------------------------------------------------------------------------
__global__ __launch_bounds__(256) void transpose_bf16(
    const ushort_t* __restrict__ in, ushort_t* __restrict__ out, int rows,
    int cols) {
  __shared__ ushort2 tile[64][65];
  const size_t slab = (size_t)rows * cols;
  const ushort2* in2 = reinterpret_cast<const ushort2*>(in + (size_t)blockIdx.z * slab);
  ushort2* out2 = reinterpret_cast<ushort2*>(out + (size_t)blockIdx.z * slab);
  const int c0 = blockIdx.x * 64;  // input col base
  const int r0 = blockIdx.y * 64;  // input row base
  const int tx = threadIdx.x & 31;
  const int ty = threadIdx.x >> 5;  // 0..7
  const int cw = cols >> 1, rw = rows >> 1;
#pragma unroll
  for (int i = ty; i < 64; i += 8)
    tile[i][tx] = in2[(size_t)(r0 + i) * cw + (c0 >> 1) + tx];
  __syncthreads();
#pragma unroll
  for (int c = ty; c < 64; c += 8) {
    ushort2 a = tile[2 * tx][c >> 1];
    ushort2 b = tile[2 * tx + 1][c >> 1];
    ushort2 o;
    o.x = (c & 1) ? a.y : a.x;
    o.y = (c & 1) ? b.y : b.x;
    out2[(size_t)(c0 + c) * rw + (r0 >> 1) + tx] = o;
  }
}

// ---------------------------------------------------------------------------
// Row softmax over 4096 columns, fp32 in -> bf16 out.  grid (rows,1,1),
// block 256; 16 values per thread in registers.
// ---------------------------------------------------------------------------
__global__ __launch_bounds__(256) void softmax_rows(
    const float* __restrict__ Sc, ushort_t* __restrict__ P) {
  const size_t base = (size_t)blockIdx.x * 4096;
  const float* row = Sc + base;
  ushort_t* prow = P + base;
  const int tid = threadIdx.x;

  float4 v[4];
#pragma unroll
  for (int i = 0; i < 4; ++i)
    v[i] = reinterpret_cast<const float4*>(row)[i * 256 + tid];

  float mx = -3.0e38f;
#pragma unroll
  for (int i = 0; i < 4; ++i)
    mx = fmaxf(mx, fmaxf(fmaxf(v[i].x, v[i].y), fmaxf(v[i].z, v[i].w)));
#pragma unroll
  for (int o = 32; o > 0; o >>= 1) mx = fmaxf(mx, __shfl_xor(mx, o, 64));

  __shared__ float redmax[4];
  __shared__ float redsum[4];
  if ((tid & 63) == 0) redmax[tid >> 6] = mx;
  __syncthreads();
  mx = fmaxf(fmaxf(redmax[0], redmax[1]), fmaxf(redmax[2], redmax[3]));

  float sum = 0.0f;
#pragma unroll
  for (int i = 0; i < 4; ++i) {
    v[i].x = __expf(v[i].x - mx);
    v[i].y = __expf(v[i].y - mx);
    v[i].z = __expf(v[i].z - mx);
    v[i].w = __expf(v[i].w - mx);
    sum += v[i].x + v[i].y + v[i].z + v[i].w;
  }
#pragma unroll
  for (int o = 32; o > 0; o >>= 1) sum += __shfl_xor(sum, o, 64);
  if ((tid & 63) == 0) redsum[tid >> 6] = sum;
  __syncthreads();
  const float inv = 1.0f / (redsum[0] + redsum[1] + redsum[2] + redsum[3]);

#pragma unroll
  for (int i = 0; i < 4; ++i) {
    ushort4v o4;
    o4.x = f32_to_bf16(v[i].x * inv);
    o4.y = f32_to_bf16(v[i].y * inv);
    o4.z = f32_to_bf16(v[i].z * inv);
    o4.w = f32_to_bf16(v[i].w * inv);
    reinterpret_cast<ushort4v*>(prow)[i * 256 + tid] = o4;
  }
}

// ---------------------------------------------------------------------------
extern "C" void kernel_launch(void* const* d_in, const int* in_sizes, int n_in,
                              void* d_out, int out_size, void* d_ws,
                              size_t ws_size, hipStream_t stream) {
  (void)in_sizes; (void)n_in; (void)out_size;

  const float* x  = (const float*)d_in[0];
  const float* Wq = (const float*)d_in[1];
  const float* bq = (const float*)d_in[2];
  const float* Wk = (const float*)d_in[3];
  const float* bk = (const float*)d_in[4];
  const float* Wv = (const float*)d_in[5];
  const float* bv = (const float*)d_in[6];
  const float* Wo = (const float*)d_in[7];
  const float* bo = (const float*)d_in[8];
  float* out = (float*)d_out;

  constexpr int BATCH = 4, S = 4096, H = 1024;
  constexpr int M = BATCH * S;                   // 16384
  constexpr size_t SZ_X = (size_t)M * H;         // 16.8M elems (33.5 MB bf16)
  constexpr size_t SZ_W = (size_t)H * H;         // 1M elems   (2 MB bf16)
  constexpr size_t SH = (size_t)S * H;           // 4.2M elems per batch
  constexpr float SCALE = 0.04419417382415922f;  // 1/sqrt(512)

  // --- workspace layout: 5 slabs + weights = ~176 MB; optional slab5 -> 210 ---
  uint8_t* w = (uint8_t*)d_ws;
  ushort_t* xb  = (ushort_t*)w; w += SZ_X * 2;   // slab0: xb -> P1
  ushort_t* wqb = (ushort_t*)w; w += SZ_W * 2;
  ushort_t* wkb = (ushort_t*)w; w += SZ_W * 2;
  ushort_t* wvb = (ushort_t*)w; w += SZ_W * 2;
  ushort_t* wob = (ushort_t*)w; w += SZ_W * 2;
  ushort_t* Qb  = (ushort_t*)w; w += SZ_X * 2;   // slab1: Q -> A (per-slot)
  ushort_t* Kb  = (ushort_t*)w; w += SZ_X * 2;   // slab2: K -> P3 (big path)
  ushort_t* Vb  = (ushort_t*)w; w += SZ_X * 2;   // slab3: V -> P0
  ushort_t* VTb = (ushort_t*)w; w += SZ_X * 2;   // slab4
  ushort_t* P2b = (ushort_t*)w;                  // slab5 (only if ws allows)
  const bool bigws = ws_size >= (size_t)(w - (uint8_t*)d_ws) + SZ_X * 2;
  float* D = out;  // scores scratch only (67 MB, exact fit)

  const dim3 blk(256);
  const Bias4 nobias = {{nullptr, nullptr, nullptr, nullptr}};
  const Alpha4 ones = {{1.0f, 1.0f, 1.0f, 1.0f}};

  // fp32 -> bf16: x, then 4 weights in one grid.z=4 dispatch
  {
    Ptr4 px = {{x, nullptr, nullptr, nullptr}};
    cvt_f32_bf16<<<dim3((unsigned)(SZ_X / 4 / 256), 1, 1), blk, 0, stream>>>(
        px, xb, 0, (int)(SZ_X / 4));
    Ptr4 pw = {{Wq, Wk, Wv, Wo}};
    cvt_f32_bf16<<<dim3((unsigned)(SZ_W / 4 / 256), 1, 4), blk, 0, stream>>>(
        pw, wqb, SZ_W, (int)(SZ_W / 4));
  }

  // fused Q/K/V projections; 1/sqrt(512) folded into Q (bq is zeros)
  {
    BPtr4 a4 = {{xb, xb, xb, xb}};
    BPtr4 b4 = {{wqb, wkb, wvb, wqb}};
    Bias4 bqkv = {{bq, bk, bv, nullptr}};
    Alpha4 al = {{SCALE, 1.0f, 1.0f, 1.0f}};
    gemm_bt<ushort_t><<<dim3(H / 128, M / 128, 3), blk, 0, stream>>>(
        a4, b4, bqkv, al, Qb, H, H, H, H, SZ_X);
  }

  // V^T per batch: [S,H] -> [H,S]
  transpose_bf16<<<dim3(H / 64, S / 64, BATCH), blk, 0, stream>>>(Vb, VTb, S, H);

  if (bigws) {
    // all four P matrices live: P0->Vb, P1->xb, P2->slab5, P3->Kb (K dead
    // after scores_3, the last K reader)
    ushort_t* Pd[4] = {Vb, xb, P2b, Kb};
    for (int b = 0; b < BATCH; ++b) {
      const ushort_t* Qp = Qb + (size_t)b * SH;
      const ushort_t* Kp = Kb + (size_t)b * SH;
      BPtr4 a4 = {{Qp, Qp, Qp, Qp}};
      BPtr4 b4 = {{Kp, Kp, Kp, Kp}};
      gemm_bt<float><<<dim3(S / 128, S / 128, 1), blk, 0, stream>>>(
          a4, b4, nobias, ones, D, H, H, H, S, 0);
      softmax_rows<<<dim3(S), blk, 0, stream>>>(D, Pd[b]);
    }
    // single PV: z = batch, 1024 blocks, Klen=4096, A_b -> dead Q slot b
    BPtr4 a4 = {{Pd[0], Pd[1], Pd[2], Pd[3]}};
    BPtr4 b4 = {{VTb, VTb + SH, VTb + 2 * SH, VTb + 3 * SH}};
    gemm_bt<ushort_t><<<dim3(H / 128, S / 128, 4), blk, 0, stream>>>(
        a4, b4, nobias, ones, Qb, S, S, S, H, SH);
  } else {
    // fallback (R6): batch pairs {2,3} then {0,1}, PV z=2 per pair
    for (int p = 1; p >= 0; --p) {
      ushort_t* Pdst[2] = {Vb, xb};
      for (int b2 = 0; b2 < 2; ++b2) {
        const int b = 2 * p + b2;
        const ushort_t* Qp = Qb + (size_t)b * SH;
        const ushort_t* Kp = Kb + (size_t)b * SH;
        BPtr4 a4 = {{Qp, Qp, Qp, Qp}};
        BPtr4 b4 = {{Kp, Kp, Kp, Kp}};
        gemm_bt<float><<<dim3(S / 128, S / 128, 1), blk, 0, stream>>>(
            a4, b4, nobias, ones, D, H, H, H, S, 0);
        softmax_rows<<<dim3(S), blk, 0, stream>>>(D, Pdst[b2]);
      }
      const ushort_t* VT0 = VTb + (size_t)(2 * p) * SH;
      const ushort_t* VT1 = VTb + (size_t)(2 * p + 1) * SH;
      BPtr4 a4 = {{Pdst[0], Pdst[1], Pdst[0], Pdst[1]}};
      BPtr4 b4 = {{VT0, VT1, VT0, VT1}};
      gemm_bt<ushort_t><<<dim3(H / 128, S / 128, 2), blk, 0, stream>>>(
          a4, b4, nobias, ones, Qb + (size_t)(2 * p) * SH, S, S, S, H, SH);
    }
  }

  // out = attn @ Wo^T + bo (fp32 out; A = Qb, packed contiguously)
  {
    BPtr4 a4 = {{Qb, Qb, Qb, Qb}};
    BPtr4 b4 = {{wob, wob, wob, wob}};
    Bias4 bb = {{bo, nullptr, nullptr, nullptr}};
    gemm_bt<float><<<dim3(H / 128, M / 128, 1), blk, 0, stream>>>(
        a4, b4, bb, ones, out, H, H, H, H, 0);
  }
}

// Round 8
// 739.052 us; speedup vs baseline: 1.0901x; 1.0901x over previous
//
#include <hip/hip_runtime.h>
#include <cstdint>
#include <cstddef>

// ---------------------------------------------------------------------------
// WaveInterference: x -> Q,K,V (Linear) -> softmax(QK^T/sqrt(512)) V -> Wo
// B=4, S=4096, H=1024.  Heavy GEMMs in bf16 MFMA (fp32 accumulate).
//
// R7 -> R8: R7 (single z=4 PV + new VT + 6th slab) regressed 761->806 with
// confounded attribution -> full revert to the R6 structure.  One change:
// scores stored as fp16 instead of fp32 (|s| <= ~9, fp16 abs err <= 5e-3),
// halving the 536 MB scores round-trip (gemm write 67->33.5 MB/batch,
// softmax read 67->33.5 MB/batch).
// ---------------------------------------------------------------------------

typedef unsigned short ushort_t;
typedef _Float16 fp16_t;
typedef __bf16 bf16x8 __attribute__((ext_vector_type(8)));
typedef _Float16 h8 __attribute__((ext_vector_type(8)));
typedef float f32x4 __attribute__((ext_vector_type(4)));
typedef unsigned short ushort4v __attribute__((ext_vector_type(4)));

struct Ptr4 { const float* p[4]; };      // cvt sources
struct BPtr4 { const ushort_t* p[4]; };  // per-z A/B operand tables
struct Bias4 { const float* p[4]; };
struct Alpha4 { float a[4]; };

__device__ __forceinline__ ushort_t f32_to_bf16(float f) {
  union { float f; unsigned int u; } x;
  x.f = f;
  unsigned int r = x.u + 0x7FFFu + ((x.u >> 16) & 1u);  // round-to-nearest-even
  return (ushort_t)(r >> 16);
}

template <typename T> __device__ __forceinline__ T cvt_out(float v);
template <> __device__ __forceinline__ float cvt_out<float>(float v) { return v; }
template <> __device__ __forceinline__ ushort_t cvt_out<ushort_t>(float v) { return f32_to_bf16(v); }
template <> __device__ __forceinline__ fp16_t cvt_out<fp16_t>(float v) { return (fp16_t)v; }

// async 16B global -> LDS (LDS dst must be wave-uniform base + lane*16)
__device__ __forceinline__ void gl2lds16(const ushort_t* g, ushort_t* l) {
  __builtin_amdgcn_global_load_lds(
      (__attribute__((address_space(1))) void*)(g),
      (__attribute__((address_space(3))) void*)(l),
      16, 0, 0);
}

// ---------------------------------------------------------------------------
// fp32 -> bf16, 4 elems/thread; grid.z selects among 4 (src, dst-slab) pairs
// ---------------------------------------------------------------------------
__global__ __launch_bounds__(256) void cvt_f32_bf16(
    Ptr4 srcs, ushort_t* __restrict__ out0, size_t zstride, int n4) {
  int i = blockIdx.x * 256 + threadIdx.x;
  if (i >= n4) return;
  const float* in = srcs.p[blockIdx.z & 3];
  ushort_t* out = out0 + zstride * blockIdx.z;
  float4 f = reinterpret_cast<const float4*>(in)[i];
  ushort4v o;
  o.x = f32_to_bf16(f.x);
  o.y = f32_to_bf16(f.y);
  o.z = f32_to_bf16(f.z);
  o.w = f32_to_bf16(f.w);
  reinterpret_cast<ushort4v*>(out)[i] = o;
}

// ---------------------------------------------------------------------------
// C[m,n] = alpha_z * sum_{k<Klen} A_z[m,k]*B_z[n,k] (+ bias_z[n]).  A,B bf16
// row-major with leading dims lda/ldb; C leading dim ldc, advanced z*zC.
// Per-z operand tables enable fused QKV (z=proj) and paired PV (z=batch).
// 128x128 tile, BK=64, 4 waves (2x2), 16x16x32 bf16 MFMA, global_load_lds
// width-16 staging, XCD band swizzle.  Requires gridDim.y % 8 == 0.
// ---------------------------------------------------------------------------
template <typename OutT>
__global__ __launch_bounds__(256, 3) void gemm_bt(
    BPtr4 a4, BPtr4 b4, Bias4 bz, Alpha4 al, OutT* __restrict__ C,
    int Klen, int lda, int ldb, int ldc, size_t zC) {
  __shared__ __align__(16) ushort_t As[128 * 64];
  __shared__ __align__(16) ushort_t Bs[128 * 64];

  const int z = blockIdx.z & 3;
  const ushort_t* __restrict__ A = a4.p[z];
  const ushort_t* __restrict__ B = b4.p[z];
  const float* bias = bz.p[z];
  const float alpha = al.a[z];
  C += (size_t)blockIdx.z * zC;

  // --- XCD band swizzle.  HW: xcd = linear_block_id % 8.  Each XCD owns a
  // horizontal band of gridDim.y/8 block-rows, walked column-major so the A
  // band stays L2-resident while B streams once per XCD. ---
  const int flat = blockIdx.x + gridDim.x * blockIdx.y;
  const int bandH = gridDim.y >> 3;
  const int xcd = flat & 7;
  const int slot = flat >> 3;
  const int bxs = slot / bandH;
  const int bys = xcd * bandH + (slot - bxs * bandH);
  const int blockRow = bys * 128;
  const int blockCol = bxs * 128;

  const int tid = threadIdx.x;
  const int lane = tid & 63;
  const int wave = tid >> 6;
  const int wm = wave >> 1;  // wave row (0..1), 64 rows each
  const int wn = wave & 1;   // wave col (0..1), 64 cols each

  // staging: each wave covers 32 rows of the 128x64 tile in 4 issues of 8 rows
  const int srow = wave * 32 + (lane >> 3);
  const int scol = (lane & 7) * 8;  // bf16 elems in the 64-wide K slab
  const ushort_t* Ag = A + (size_t)(blockRow + srow) * lda + scol;
  const ushort_t* Bg = B + (size_t)(blockCol + srow) * ldb + scol;
  ushort_t* Al = &As[srow * 64 + scol];  // = As + (wavebase + lane*16B)
  ushort_t* Bl = &Bs[srow * 64 + scol];

  const int lm = lane & 15;    // m (A frag) / n (B frag)
  const int quad = lane >> 4;  // 0..3 -> k offset quad*8

  f32x4 acc[4][4] = {};

  for (int k0 = 0; k0 < Klen; k0 += 64) {
#pragma unroll
    for (int j = 0; j < 4; ++j) {
      gl2lds16(Ag + (size_t)j * 8 * lda + k0, Al + j * 8 * 64);
      gl2lds16(Bg + (size_t)j * 8 * ldb + k0, Bl + j * 8 * 64);
    }
    __syncthreads();  // compiler emits vmcnt(0) drain before barrier
#pragma unroll
    for (int kk = 0; kk < 64; kk += 32) {
      bf16x8 af[4], bfr[4];
#pragma unroll
      for (int i = 0; i < 4; ++i) {
        af[i] = *reinterpret_cast<const bf16x8*>(
            &As[(wm * 64 + i * 16 + lm) * 64 + kk + quad * 8]);
        bfr[i] = *reinterpret_cast<const bf16x8*>(
            &Bs[(wn * 64 + i * 16 + lm) * 64 + kk + quad * 8]);
      }
#pragma unroll
      for (int i = 0; i < 4; ++i)
#pragma unroll
        for (int j = 0; j < 4; ++j)
          acc[i][j] = __builtin_amdgcn_mfma_f32_16x16x32_bf16(
              af[i], bfr[j], acc[i][j], 0, 0, 0);
    }
    __syncthreads();
  }

  // epilogue: C/D layout col = lane&15 (n), row = quad*4 + reg (m)
  const int mBase = blockRow + wm * 64 + quad * 4;
  const int nBase = blockCol + wn * 64 + lm;
#pragma unroll
  for (int j = 0; j < 4; ++j) {
    const int n = nBase + j * 16;
    const float bv = bias ? bias[n] : 0.0f;
#pragma unroll
    for (int i = 0; i < 4; ++i) {
#pragma unroll
      for (int r = 0; r < 4; ++r) {
        const int m = mBase + i * 16 + r;
        C[(size_t)m * ldc + n] = cvt_out<OutT>(acc[i][j][r] * alpha + bv);
      }
    }
  }
}

// ---------------------------------------------------------------------------
// bf16 transpose: out[c][r] = in[r][c], per-batch slab of rows*cols.
// ---------------------------------------------------------------------------
__global__ __launch_bounds__(256) void transpose_bf16(
    const ushort_t* __restrict__ in, ushort_t* __restrict__ out, int rows,
    int cols) {
  __shared__ ushort_t tile[32][33];
  const size_t slab = (size_t)rows * cols;
  in += (size_t)blockIdx.z * slab;
  out += (size_t)blockIdx.z * slab;
  const int c0 = blockIdx.x * 32;
  const int r0 = blockIdx.y * 32;
  const int tx = threadIdx.x & 31;
  const int ty = threadIdx.x >> 5;  // 0..7
#pragma unroll
  for (int i = ty; i < 32; i += 8)
    tile[i][tx] = in[(size_t)(r0 + i) * cols + (c0 + tx)];
  __syncthreads();
#pragma unroll
  for (int i = ty; i < 32; i += 8)
    out[(size_t)(c0 + i) * rows + (r0 + tx)] = tile[tx][i];
}

// ---------------------------------------------------------------------------
// Row softmax over 4096 columns, fp16 in -> bf16 out.  grid (rows,1,1),
// block 256; 16 values per thread in registers (two 16B vector loads).
// ---------------------------------------------------------------------------
__global__ __launch_bounds__(256) void softmax_rows(
    const fp16_t* __restrict__ Sc, ushort_t* __restrict__ P) {
  const size_t base = (size_t)blockIdx.x * 4096;
  const fp16_t* row = Sc + base;
  ushort_t* prow = P + base;
  const int tid = threadIdx.x;

  h8 h[2];
  h[0] = reinterpret_cast<const h8*>(row)[tid];        // elems [8t, 8t+8)
  h[1] = reinterpret_cast<const h8*>(row)[tid + 256];  // elems [8(t+256)..)
  float v[16];
#pragma unroll
  for (int i = 0; i < 2; ++i)
#pragma unroll
    for (int j = 0; j < 8; ++j) v[i * 8 + j] = (float)h[i][j];

  float mx = -3.0e38f;
#pragma unroll
  for (int i = 0; i < 16; ++i) mx = fmaxf(mx, v[i]);
#pragma unroll
  for (int o = 32; o > 0; o >>= 1) mx = fmaxf(mx, __shfl_xor(mx, o, 64));

  __shared__ float redmax[4];
  __shared__ float redsum[4];
  if ((tid & 63) == 0) redmax[tid >> 6] = mx;
  __syncthreads();
  mx = fmaxf(fmaxf(redmax[0], redmax[1]), fmaxf(redmax[2], redmax[3]));

  float sum = 0.0f;
#pragma unroll
  for (int i = 0; i < 16; ++i) {
    v[i] = __expf(v[i] - mx);
    sum += v[i];
  }
#pragma unroll
  for (int o = 32; o > 0; o >>= 1) sum += __shfl_xor(sum, o, 64);
  if ((tid & 63) == 0) redsum[tid >> 6] = sum;
  __syncthreads();
  const float inv = 1.0f / (redsum[0] + redsum[1] + redsum[2] + redsum[3]);

  // write bf16, same element mapping as the loads
#pragma unroll
  for (int i = 0; i < 2; ++i) {
    const int vbase = (i == 0) ? tid : (tid + 256);  // h8 granule index
#pragma unroll
    for (int q = 0; q < 2; ++q) {
      ushort4v o4;
      o4.x = f32_to_bf16(v[i * 8 + q * 4 + 0] * inv);
      o4.y = f32_to_bf16(v[i * 8 + q * 4 + 1] * inv);
      o4.z = f32_to_bf16(v[i * 8 + q * 4 + 2] * inv);
      o4.w = f32_to_bf16(v[i * 8 + q * 4 + 3] * inv);
      reinterpret_cast<ushort4v*>(prow)[2 * vbase + q] = o4;
    }
  }
}

// ---------------------------------------------------------------------------
extern "C" void kernel_launch(void* const* d_in, const int* in_sizes, int n_in,
                              void* d_out, int out_size, void* d_ws,
                              size_t ws_size, hipStream_t stream) {
  (void)in_sizes; (void)n_in; (void)out_size; (void)ws_size;

  const float* x  = (const float*)d_in[0];
  const float* Wq = (const float*)d_in[1];
  const float* bq = (const float*)d_in[2];
  const float* Wk = (const float*)d_in[3];
  const float* bk = (const float*)d_in[4];
  const float* Wv = (const float*)d_in[5];
  const float* bv = (const float*)d_in[6];
  const float* Wo = (const float*)d_in[7];
  const float* bo = (const float*)d_in[8];
  float* out = (float*)d_out;

  constexpr int BATCH = 4, S = 4096, H = 1024;
  constexpr int M = BATCH * S;                   // 16384
  constexpr size_t SZ_X = (size_t)M * H;         // 16.8M elems (33.5 MB bf16)
  constexpr size_t SZ_W = (size_t)H * H;         // 1M elems   (2 MB bf16)
  constexpr size_t SH = (size_t)S * H;           // 4.2M elems per batch
  constexpr float SCALE = 0.04419417382415922f;  // 1/sqrt(512)

  // --- workspace layout: 5 slabs + 4 weight buffers = ~176 MB total ---
  uint8_t* w = (uint8_t*)d_ws;
  ushort_t* xb  = (ushort_t*)w; w += SZ_X * 2;   // slab0: xb -> P1
  ushort_t* wqb = (ushort_t*)w; w += SZ_W * 2;
  ushort_t* wkb = (ushort_t*)w; w += SZ_W * 2;
  ushort_t* wvb = (ushort_t*)w; w += SZ_W * 2;
  ushort_t* wob = (ushort_t*)w; w += SZ_W * 2;
  ushort_t* Qb  = (ushort_t*)w; w += SZ_X * 2;   // slab1: Q -> A (per-slot)
  ushort_t* Kb  = (ushort_t*)w; w += SZ_X * 2;   // slab2
  ushort_t* Vb  = (ushort_t*)w; w += SZ_X * 2;   // slab3: Vb -> P0
  ushort_t* VTb = (ushort_t*)w; w += SZ_X * 2;   // slab4
  fp16_t* D = (fp16_t*)out;  // fp16 scores scratch (33.5 MB of the 67 MB out)

  const dim3 blk(256);
  const Bias4 nobias = {{nullptr, nullptr, nullptr, nullptr}};
  const Alpha4 ones = {{1.0f, 1.0f, 1.0f, 1.0f}};

  // fp32 -> bf16: x, then 4 weights in one grid.z=4 dispatch
  {
    Ptr4 px = {{x, nullptr, nullptr, nullptr}};
    cvt_f32_bf16<<<dim3((unsigned)(SZ_X / 4 / 256), 1, 1), blk, 0, stream>>>(
        px, xb, 0, (int)(SZ_X / 4));
    Ptr4 pw = {{Wq, Wk, Wv, Wo}};
    cvt_f32_bf16<<<dim3((unsigned)(SZ_W / 4 / 256), 1, 4), blk, 0, stream>>>(
        pw, wqb, SZ_W, (int)(SZ_W / 4));
  }

  // fused Q/K/V projections; 1/sqrt(512) folded into Q (bq is zeros)
  {
    BPtr4 a4 = {{xb, xb, xb, xb}};
    BPtr4 b4 = {{wqb, wkb, wvb, wqb}};
    Bias4 bqkv = {{bq, bk, bv, nullptr}};
    Alpha4 al = {{SCALE, 1.0f, 1.0f, 1.0f}};
    gemm_bt<ushort_t><<<dim3(H / 128, M / 128, 3), blk, 0, stream>>>(
        a4, b4, bqkv, al, Qb, H, H, H, H, SZ_X);
  }

  // V^T per batch: [S,H] -> [H,S]
  transpose_bf16<<<dim3(H / 32, S / 32, BATCH), blk, 0, stream>>>(Vb, VTb, S, H);

  // attention in batch pairs, {2,3} first so A_b can reuse dead Q slots
  for (int p = 1; p >= 0; --p) {
    ushort_t* Pdst[2] = {Vb, xb};  // Vb dead after VT; xb dead after QKV
    for (int b2 = 0; b2 < 2; ++b2) {
      const int b = 2 * p + b2;
      const ushort_t* Qp = Qb + (size_t)b * SH;
      const ushort_t* Kp = Kb + (size_t)b * SH;
      BPtr4 a4 = {{Qp, Qp, Qp, Qp}};
      BPtr4 b4 = {{Kp, Kp, Kp, Kp}};
      gemm_bt<fp16_t><<<dim3(S / 128, S / 128, 1), blk, 0, stream>>>(
          a4, b4, nobias, ones, D, H, H, H, S, 0);
      softmax_rows<<<dim3(S), blk, 0, stream>>>(D, Pdst[b2]);
    }
    // paired PV: z = batch-in-pair, Klen=4096, 512 blocks, bf16 A written
    // into the pair's dead Q slots (Qb + (2p+z)*SH)
    {
      const ushort_t* VT0 = VTb + (size_t)(2 * p) * SH;
      const ushort_t* VT1 = VTb + (size_t)(2 * p + 1) * SH;
      BPtr4 a4 = {{Pdst[0], Pdst[1], Pdst[0], Pdst[1]}};
      BPtr4 b4 = {{VT0, VT1, VT0, VT1}};
      gemm_bt<ushort_t><<<dim3(H / 128, S / 128, 2), blk, 0, stream>>>(
          a4, b4, nobias, ones, Qb + (size_t)(2 * p) * SH, S, S, S, H, SH);
    }
  }

  // out = attn @ Wo^T + bo (fp32 out; A = Qb, packed contiguously)
  {
    BPtr4 a4 = {{Qb, Qb, Qb, Qb}};
    BPtr4 b4 = {{wob, wob, wob, wob}};
    Bias4 bb = {{bo, nullptr, nullptr, nullptr}};
    gemm_bt<float><<<dim3(H / 128, M / 128, 1), blk, 0, stream>>>(
        a4, b4, bb, ones, out, H, H, H, H, 0);
  }
}